// Round 8
// baseline (264.436 us; speedup 1.0000x reference)
//
#include <hip/hip_runtime.h>
#include <math.h>

#define NN 256
#define CZ 128
#define NH 4
#define CH 32
#define HC 128
#define NPIX (NN*NN)
#define L2E   1.4426950408889634f
#define SCALE2 (0.17677669529663687f * 1.4426950408889634f)   // (1/sqrt(32))*log2e

typedef __attribute__((ext_vector_type(8))) short bf16x8;   // 8 bf16 (4 VGPRs)
typedef __attribute__((ext_vector_type(4))) float fx4;      // MFMA accumulator
typedef __attribute__((ext_vector_type(4))) unsigned u32x4;

// --- cheap truncation split: x ~= hi + lo, total err ~2^-16 relative ---
__device__ __forceinline__ unsigned pack_hl(float x) {
    unsigned b  = __builtin_bit_cast(unsigned, x);
    unsigned hb = b & 0xFFFF0000u;
    float r = x - __builtin_bit_cast(float, hb);
    return hb | (__builtin_bit_cast(unsigned, r) >> 16);   // hi in top16, lo in bottom16
}
// load 8 consecutive floats -> hi/lo bf16x8 fragments (trunc split, ~4 VALU/elem)
__device__ __forceinline__ void load_split8(const float* p, bf16x8& h, bf16x8& l) {
    float4 x0 = *(const float4*)p;
    float4 x1 = *(const float4*)(p + 4);
    float xs[8] = {x0.x, x0.y, x0.z, x0.w, x1.x, x1.y, x1.z, x1.w};
    #pragma unroll
    for (int j = 0; j < 8; ++j) {
        unsigned b  = __builtin_bit_cast(unsigned, xs[j]);
        unsigned hb = b & 0xFFFF0000u;
        float r = xs[j] - __builtin_bit_cast(float, hb);
        h[j] = (short)(hb >> 16);
        l[j] = (short)(__builtin_bit_cast(unsigned, r) >> 16);
    }
}
// deinterleave 8 packed uint32 (hi|lo) held in registers -> hi/lo bf16x8 frags
__device__ __forceinline__ void deint_raw(u32x4 e0, u32x4 e1, bf16x8& h, bf16x8& l) {
    unsigned es[8] = {e0[0], e0[1], e0[2], e0[3], e1[0], e1[1], e1[2], e1[3]};
    unsigned hw[4], lw[4];
    #pragma unroll
    for (int j = 0; j < 4; ++j) {
        unsigned a = es[2 * j], b = es[2 * j + 1];
        hw[j] = (a >> 16) | (b & 0xFFFF0000u);
        lw[j] = (a & 0x0000FFFFu) | (b << 16);
    }
    h = __builtin_bit_cast(bf16x8, u32x4{hw[0], hw[1], hw[2], hw[3]});
    l = __builtin_bit_cast(bf16x8, u32x4{lw[0], lw[1], lw[2], lw[3]});
}
// load 8 packed uint32 (hi|lo) -> hi/lo bf16x8 fragments
__device__ __forceinline__ void deint8(const unsigned* p, bf16x8& h, bf16x8& l) {
    u32x4 e0 = *(const u32x4*)p;
    u32x4 e1 = *(const u32x4*)(p + 4);
    deint_raw(e0, e1, h, l);
}

// 2x2x2 quad transpose across lanes (gfx950 dual-dest lane swaps, no LDS).
__device__ __forceinline__ void qtrans(unsigned &x, unsigned &y) {
#if __has_builtin(__builtin_amdgcn_permlane32_swap) && __has_builtin(__builtin_amdgcn_permlane16_swap)
    {
        auto r = __builtin_amdgcn_permlane32_swap(x, y, false, false);
        x = r[0]; y = r[1];
    }
    {
        auto r = __builtin_amdgcn_permlane16_swap(x, y, false, false);
        x = r[0]; y = r[1];
    }
#else
    asm("v_permlane32_swap_b32 %0, %1\n\t"
        "v_permlane16_swap_b32 %0, %1" : "+v"(x), "+v"(y));
#endif
}

// ---------------------------------------------------------------------------
// Kernel 0: pack weights into MFMA B-fragment layout, bf16 hi/lo planes.
// B-frag (16x16x32): lane holds B[k][n], n=lane&15, k=quad*8+j.
// entry index: (kstep*128 + n)*4 + quad. 0=Wq 1=Wk 2=Wv 3=Wg 4=Wo.
// ---------------------------------------------------------------------------
__global__ __launch_bounds__(256) void pack_w_kernel(
    const float* __restrict__ Wq, const float* __restrict__ Wk,
    const float* __restrict__ Wv, const float* __restrict__ Wg,
    const float* __restrict__ Wo, bf16x8* __restrict__ pk)
{
    int id  = blockIdx.x * 256 + threadIdx.x;
    int mid = id >> 11;
    int e   = id & 2047;
    const float* W = (mid == 0) ? Wq : (mid == 1) ? Wk : (mid == 2) ? Wv : (mid == 3) ? Wg : Wo;
    int quad = e & 3, n = (e >> 2) & 127, ks = e >> 9;
    int k0 = ks * 32 + quad * 8;
    bf16x8 h, l;
    #pragma unroll
    for (int j = 0; j < 8; ++j) {
        float x = W[(size_t)(k0 + j) * 128 + n];
        unsigned b  = __builtin_bit_cast(unsigned, x);
        unsigned hb = b & 0xFFFF0000u;
        float r = x - __builtin_bit_cast(float, hb);
        h[j] = (short)(hb >> 16);
        l[j] = (short)(__builtin_bit_cast(unsigned, r) >> 16);
    }
    pk[(size_t)mid * 4096 + e]        = h;
    pk[(size_t)mid * 4096 + 2048 + e] = l;
}

// ---------------------------------------------------------------------------
// Kernel 1: fused LayerNorm + projections via split-bf16 MFMA.
// (unchanged from round 4)
// ---------------------------------------------------------------------------
__global__ __launch_bounds__(256) void ln_proj_kernel(
    const float* __restrict__ z, const float* __restrict__ ls, const float* __restrict__ lb,
    const float* __restrict__ Wb, const bf16x8* __restrict__ pk,
    unsigned* __restrict__ q_pk, unsigned* __restrict__ k_pk, unsigned* __restrict__ v_pk,
    float* __restrict__ g_ws, float* __restrict__ bias_n)
{
    __shared__ float zsh[32][132];
    __shared__ float wbsh[512];

    const int t  = threadIdx.x;
    const int p0 = blockIdx.x * 32;
    const int i  = p0 >> 8;
    const int j0 = p0 & 255;

    // stage Wb (128x4 floats) into LDS alongside the z loads
    wbsh[t]       = Wb[t];
    wbsh[t + 256] = Wb[t + 256];

    // thread owns 16 channels (sub*16..) of pixel p = t>>3
    const int p = t >> 3, sub = t & 7;
    float4 zv[4];
    {
        const float4* zp = (const float4*)(z + (size_t)(p0 + p) * CZ + sub * 16);
        #pragma unroll
        for (int r = 0; r < 4; ++r) zv[r] = zp[r];
    }
    float s = 0.f, q = 0.f;
    #pragma unroll
    for (int r = 0; r < 4; ++r) {
        s += ((zv[r].x + zv[r].y) + (zv[r].z + zv[r].w));
        q += ((zv[r].x * zv[r].x + zv[r].y * zv[r].y)
            + (zv[r].z * zv[r].z + zv[r].w * zv[r].w));
    }
    // reduce across the 8 threads of this pixel (lane bits 0..2)
    #pragma unroll
    for (int m = 1; m <= 4; m <<= 1) {
        s += __shfl_xor(s, m, 64);
        q += __shfl_xor(q, m, 64);
    }
    {
        float mu  = s * (1.0f / 128.0f);
        float var = q * (1.0f / 128.0f) - mu * mu;
        float a   = var + 1e-5f;
        float r0  = rsqrtf(a);
        r0 = r0 * (1.5f - 0.5f * a * r0 * r0);
        #pragma unroll
        for (int r = 0; r < 4; ++r) {
            float4 s4 = ((const float4*)ls)[sub * 4 + r];
            float4 b4 = ((const float4*)lb)[sub * 4 + r];
            float4 v  = zv[r];
            v.x = (v.x - mu) * r0 * s4.x + b4.x;
            v.y = (v.y - mu) * r0 * s4.y + b4.y;
            v.z = (v.z - mu) * r0 * s4.z + b4.z;
            v.w = (v.w - mu) * r0 * s4.w + b4.w;
            *(float4*)&zsh[p][sub * 16 + r * 4] = v;
        }
    }
    __syncthreads();   // the ONLY barrier

    const int wv = t >> 6, lane = t & 63;
    const int lrow = lane & 15, quad = lane >> 4;
    const bf16x8* ph = pk + (size_t)wv * 4096;
    const bf16x8* pl = ph + 2048;

    fx4 acc[2][8];
    #pragma unroll
    for (int mr = 0; mr < 2; ++mr)
        #pragma unroll
        for (int nc = 0; nc < 8; ++nc)
            acc[mr][nc] = fx4{0.f, 0.f, 0.f, 0.f};

    #pragma unroll
    for (int ks = 0; ks < 4; ++ks) {
        bf16x8 ah[2], al[2];
        #pragma unroll
        for (int mr = 0; mr < 2; ++mr)
            load_split8(&zsh[mr * 16 + lrow][ks * 32 + quad * 8], ah[mr], al[mr]);
        #pragma unroll
        for (int nc = 0; nc < 8; ++nc) {
            int bi = (ks * 128 + nc * 16 + lrow) * 4 + quad;
            bf16x8 bh = ph[bi], bl = pl[bi];
            #pragma unroll
            for (int mr = 0; mr < 2; ++mr) {
                acc[mr][nc] = __builtin_amdgcn_mfma_f32_16x16x32_bf16(ah[mr], bl, acc[mr][nc], 0, 0, 0);
                acc[mr][nc] = __builtin_amdgcn_mfma_f32_16x16x32_bf16(al[mr], bh, acc[mr][nc], 0, 0, 0);
                acc[mr][nc] = __builtin_amdgcn_mfma_f32_16x16x32_bf16(ah[mr], bh, acc[mr][nc], 0, 0, 0);
            }
        }
    }

    // epilogue: C layout col=lane&15, row=quad*4+reg
    #pragma unroll
    for (int mr = 0; mr < 2; ++mr) {
        #pragma unroll
        for (int nc = 0; nc < 8; ++nc) {
            int cg = nc * 16 + lrow;          // channel 0..127
            int h = cg >> 5, cc = cg & 31;
            int jl = mr * 16 + quad * 4;      // local pixel base (4 consecutive)
            fx4 a = acc[mr][nc];
            if (wv == 0) {                    // q packed [j][c]
                unsigned* qp = q_pk + ((size_t)(i * NH + h) * NN + j0 + jl) * CH + cc;
                #pragma unroll
                for (int r = 0; r < 4; ++r) qp[r * CH] = pack_hl(a[r]);
            } else if (wv == 1) {             // k packed [j][c]
                unsigned* kp = k_pk + ((size_t)(i * NH + h) * NN + j0 + jl) * CH + cc;
                #pragma unroll
                for (int r = 0; r < 4; ++r) kp[r * CH] = pack_hl(a[r]);
            } else if (wv == 2) {             // v packed transposed [c][j]
                u32x4 e = {pack_hl(a[0]), pack_hl(a[1]), pack_hl(a[2]), pack_hl(a[3])};
                *(u32x4*)(v_pk + ((size_t)(i * NH + h) * CH + cc) * NN + j0 + jl) = e;
            } else {                          // g (fp32)
                float* gp = g_ws + (size_t)(p0 + jl) * HC + cg;
                #pragma unroll
                for (int r = 0; r < 4; ++r) gp[r * HC] = 1.0f / (1.0f + __expf(-a[r]));
            }
        }
    }

    // bias = zn @ Wb * log2e; 2 threads per (hh,p): 64-deep halves + pair add
    {
        int pair = t >> 1, half = t & 1;
        int hh = pair >> 5, pp = pair & 31;
        int d0 = half * 64;
        float b = 0.f;
        #pragma unroll 8
        for (int d = 0; d < 64; ++d)
            b = fmaf(zsh[pp][d0 + d], wbsh[(d0 + d) * 4 + hh], b);
        b += __shfl_xor(b, 1, 64);
        if (half == 0)
            bias_n[(size_t)hh * NPIX + (size_t)i * NN + j0 + pp] = b * L2E;
    }
}

// ---------------------------------------------------------------------------
// Kernel 2: MFMA flash attention + FUSED output projection.
// Round-8: occupancy attack. Three schedules + traffic fix all landed at the
// same time with MfmaUtil ~12% / VALUBusy ~36% / Occupancy ~21% -> the kernel
// is latency-bound with too few resident waves. Halve the per-block query
// window (64 -> 32, nt 4 -> 2): grid 1024 -> 2048 (8 blocks/CU), ~half the
// live registers per wave, LDS 33.8 -> 16.9 KB. Main-loop math per value is
// byte-identical (same order) -> absmax unchanged.
// Block = (i, jb in 0..7); WAVE = HEAD. XCD swizzle (bijective, nwg=2048):
// jb=(d>>3)&7, i=(d&7)+8*(d>>6) -- the 8 jb-blocks of row i run consecutively
// on one XCD so K/V re-reads stay L2-resident (round-7: FETCH 176->77 MB).
// Fused outproj: wave wv does pixel-tile (wv&1) x channel-half (wv>>1).
// NOTE: plain __launch_bounds__(256) -- (256,4) forced 64-VGPR cap + spill.
// ---------------------------------------------------------------------------
__global__ __launch_bounds__(256) void attn_kernel(
    const unsigned* __restrict__ q_pk, const unsigned* __restrict__ k_pk,
    const unsigned* __restrict__ v_pk, const float* __restrict__ g_ws,
    const float* __restrict__ bias_n, const bf16x8* __restrict__ pk,
    float* __restrict__ out)
{
    __shared__ float gsh[32][132];

    const int t = threadIdx.x;
    const int wv = t >> 6, lane = t & 63;
    const int lrow = lane & 15, quad = lane >> 4;
    // XCD-aware swizzle: 8 jb-blocks of each row i share an XCD, consecutive.
    const int d  = blockIdx.x;
    const int jb = (d >> 3) & 7;
    const int i  = (d & 7) + 8 * (d >> 6);
    const int h = wv;            // wave = head
    const int qb = jb * 32;      // shared 32-query window

    const unsigned* qs = q_pk + (size_t)(i * NH + h) * NN * CH;
    const unsigned* ks = k_pk + (size_t)(i * NH + h) * NN * CH;
    const unsigned* vs = v_pk + (size_t)(i * NH + h) * CH * NN;
    const float*    bs = bias_n + (size_t)h * NPIX;

    bf16x8 qh[2], ql[2];
    #pragma unroll
    for (int nt = 0; nt < 2; ++nt)
        deint8(qs + (size_t)(qb + nt * 16 + lrow) * CH + quad * 8, qh[nt], ql[nt]);

    u32x4 krA[2], krB[2];
    #pragma unroll
    for (int mt = 0; mt < 2; ++mt) {
        const u32x4* kp = (const u32x4*)(ks + (size_t)(mt * 16 + lrow) * CH + quad * 8);
        krA[mt] = kp[0]; krB[mt] = kp[1];
    }

    fx4 oacc[2][2];
    #pragma unroll
    for (int ct = 0; ct < 2; ++ct)
        #pragma unroll
        for (int nt = 0; nt < 2; ++nt)
            oacc[ct][nt] = fx4{0.f, 0.f, 0.f, 0.f};
    float lsum[2] = {0.f, 0.f};

    for (int kb = 0; kb < NN; kb += 32) {
        u32x4 vrA[2], vrB[2];
        #pragma unroll
        for (int ct = 0; ct < 2; ++ct) {
            const u32x4* vp = (const u32x4*)(vs + (size_t)(ct * 16 + lrow) * NN + kb + quad * 8);
            vrA[ct] = vp[0]; vrB[ct] = vp[1];
        }
        float4 bv[2][2];
        #pragma unroll
        for (int nt = 0; nt < 2; ++nt)
            #pragma unroll
            for (int mt = 0; mt < 2; ++mt)
                bv[nt][mt] = *(const float4*)(bs + (size_t)(qb + nt * 16 + lrow) * NN
                                                 + kb + mt * 16 + quad * 4);
        const int kb2 = (kb + 32) & (NN - 1);
        u32x4 nkA[2], nkB[2];
        #pragma unroll
        for (int mt = 0; mt < 2; ++mt) {
            const u32x4* kp = (const u32x4*)(ks + (size_t)(kb2 + mt * 16 + lrow) * CH + quad * 8);
            nkA[mt] = kp[0]; nkB[mt] = kp[1];
        }

        bf16x8 kh[2], kl_[2];
        #pragma unroll
        for (int mt = 0; mt < 2; ++mt)
            deint_raw(krA[mt], krB[mt], kh[mt], kl_[mt]);

        fx4 sv[2][2];
        __builtin_amdgcn_s_setprio(1);
        #pragma unroll
        for (int nt = 0; nt < 2; ++nt) {
            #pragma unroll
            for (int mt = 0; mt < 2; ++mt) {
                fx4 s = fx4{0.f, 0.f, 0.f, 0.f};
                s = __builtin_amdgcn_mfma_f32_16x16x32_bf16(kh[mt],  ql[nt], s, 0, 0, 0);
                s = __builtin_amdgcn_mfma_f32_16x16x32_bf16(kl_[mt], qh[nt], s, 0, 0, 0);
                s = __builtin_amdgcn_mfma_f32_16x16x32_bf16(kh[mt],  qh[nt], s, 0, 0, 0);
                sv[nt][mt] = s;
            }
        }
        __builtin_amdgcn_s_setprio(0);

        bf16x8 vh[2], vl[2];
        #pragma unroll
        for (int ct = 0; ct < 2; ++ct)
            deint_raw(vrA[ct], vrB[ct], vh[ct], vl[ct]);

        unsigned w0h[2][2], w1h[2][2], w0l[2][2], w1l[2][2];
        #pragma unroll
        for (int nt = 0; nt < 2; ++nt) {
            #pragma unroll
            for (int mt = 0; mt < 2; ++mt) {
                fx4 s = sv[nt][mt];
                float4 b4 = bv[nt][mt];
                float e0 = exp2f(fmaf(s[0], SCALE2, b4.x));
                float e1 = exp2f(fmaf(s[1], SCALE2, b4.y));
                float e2 = exp2f(fmaf(s[2], SCALE2, b4.z));
                float e3 = exp2f(fmaf(s[3], SCALE2, b4.w));
                lsum[nt] += (e0 + e1) + (e2 + e3);

                unsigned b0 = __builtin_bit_cast(unsigned, e0);
                unsigned b1 = __builtin_bit_cast(unsigned, e1);
                unsigned b2 = __builtin_bit_cast(unsigned, e2);
                unsigned b3 = __builtin_bit_cast(unsigned, e3);
                unsigned h01 = (b0 >> 16) | (b1 & 0xFFFF0000u);
                unsigned h23 = (b2 >> 16) | (b3 & 0xFFFF0000u);
                float r0 = e0 - __builtin_bit_cast(float, b0 & 0xFFFF0000u);
                float r1 = e1 - __builtin_bit_cast(float, b1 & 0xFFFF0000u);
                float r2 = e2 - __builtin_bit_cast(float, b2 & 0xFFFF0000u);
                float r3 = e3 - __builtin_bit_cast(float, b3 & 0xFFFF0000u);
                unsigned l01 = (__builtin_bit_cast(unsigned, r0) >> 16)
                             | (__builtin_bit_cast(unsigned, r1) & 0xFFFF0000u);
                unsigned l23 = (__builtin_bit_cast(unsigned, r2) >> 16)
                             | (__builtin_bit_cast(unsigned, r3) & 0xFFFF0000u);
                w0h[nt][mt] = h01; w1h[nt][mt] = h23;
                w0l[nt][mt] = l01; w1l[nt][mt] = l23;
            }
        }

        #pragma unroll
        for (int nt = 0; nt < 2; ++nt) {
            qtrans(w0h[nt][0], w0h[nt][1]);
            qtrans(w1h[nt][0], w1h[nt][1]);
            qtrans(w0l[nt][0], w0l[nt][1]);
            qtrans(w1l[nt][0], w1l[nt][1]);
        }

        __builtin_amdgcn_s_setprio(1);
        #pragma unroll
        for (int nt = 0; nt < 2; ++nt) {
            bf16x8 pbh = __builtin_bit_cast(bf16x8,
                u32x4{w0h[nt][0], w1h[nt][0], w0h[nt][1], w1h[nt][1]});
            bf16x8 pbl = __builtin_bit_cast(bf16x8,
                u32x4{w0l[nt][0], w1l[nt][0], w0l[nt][1], w1l[nt][1]});
            #pragma unroll
            for (int ct = 0; ct < 2; ++ct) {
                oacc[ct][nt] = __builtin_amdgcn_mfma_f32_16x16x32_bf16(vh[ct], pbl, oacc[ct][nt], 0, 0, 0);
                oacc[ct][nt] = __builtin_amdgcn_mfma_f32_16x16x32_bf16(vl[ct], pbh, oacc[ct][nt], 0, 0, 0);
                oacc[ct][nt] = __builtin_amdgcn_mfma_f32_16x16x32_bf16(vh[ct], pbh, oacc[ct][nt], 0, 0, 0);
            }
        }
        __builtin_amdgcn_s_setprio(0);

        #pragma unroll
        for (int mt = 0; mt < 2; ++mt) { krA[mt] = nkA[mt]; krB[mt] = nkB[mt]; }
    }

    // gate epilogue -> LDS [local pixel][channel]; channels h*32..h*32+31
    #pragma unroll
    for (int nt = 0; nt < 2; ++nt) {
        float s = lsum[nt];
        s += __shfl_xor(s, 16, 64);
        s += __shfl_xor(s, 32, 64);
        float inv = 1.0f / s;
        size_t pix = (size_t)i * NN + qb + nt * 16 + lrow;
        #pragma unroll
        for (int ct = 0; ct < 2; ++ct) {
            const float* gp = g_ws + pix * HC + h * CH + ct * 16 + quad * 4;
            float4 g4 = *(const float4*)gp;
            fx4 o = oacc[ct][nt];
            float4 r;
            r.x = g4.x * o[0] * inv;
            r.y = g4.y * o[1] * inv;
            r.z = g4.z * o[2] * inv;
            r.w = g4.w * o[3] * inv;
            *(float4*)&gsh[nt * 16 + lrow][h * CH + ct * 16 + quad * 4] = r;
        }
    }
    __syncthreads();   // only barrier in the kernel

    // fused outproj: wave wv -> pixel-tile pt=wv&1 (16 pixels), nc-half nh=wv>>1
    {
        const bf16x8* ph = pk + (size_t)4 * 4096;   // Wo
        const bf16x8* pl = ph + 2048;
        const int pt = wv & 1, nh = wv >> 1;

        bf16x8 ah[4], al[4];
        #pragma unroll
        for (int ksx = 0; ksx < 4; ++ksx)
            load_split8(&gsh[pt * 16 + lrow][ksx * 32 + quad * 8], ah[ksx], al[ksx]);

        fx4 acc[4];
        #pragma unroll
        for (int nc = 0; nc < 4; ++nc) acc[nc] = fx4{0.f, 0.f, 0.f, 0.f};

        #pragma unroll
        for (int ksx = 0; ksx < 4; ++ksx) {
            #pragma unroll
            for (int nc2 = 0; nc2 < 4; ++nc2) {
                int nc = nh * 4 + nc2;
                int bi = (ksx * 128 + nc * 16 + lrow) * 4 + quad;
                bf16x8 bh = ph[bi], bl = pl[bi];
                acc[nc2] = __builtin_amdgcn_mfma_f32_16x16x32_bf16(ah[ksx], bl, acc[nc2], 0, 0, 0);
                acc[nc2] = __builtin_amdgcn_mfma_f32_16x16x32_bf16(al[ksx], bh, acc[nc2], 0, 0, 0);
                acc[nc2] = __builtin_amdgcn_mfma_f32_16x16x32_bf16(ah[ksx], bh, acc[nc2], 0, 0, 0);
            }
        }

        const size_t prow = (size_t)i * NN + qb;
        #pragma unroll
        for (int nc2 = 0; nc2 < 4; ++nc2) {
            int nc = nh * 4 + nc2;
            #pragma unroll
            for (int r = 0; r < 4; ++r)
                out[(prow + pt * 16 + quad * 4 + r) * HC + nc * 16 + lrow] = acc[nc2][r];
        }
    }
}

// ---------------------------------------------------------------------------
extern "C" void kernel_launch(void* const* d_in, const int* in_sizes, int n_in,
                              void* d_out, int out_size, void* d_ws, size_t ws_size,
                              hipStream_t stream)
{
    const float* z  = (const float*)d_in[0];
    const float* ls = (const float*)d_in[1];
    const float* lb = (const float*)d_in[2];
    const float* Wq = (const float*)d_in[3];
    const float* Wk = (const float*)d_in[4];
    const float* Wv = (const float*)d_in[5];
    const float* Wb = (const float*)d_in[6];
    const float* Wg = (const float*)d_in[7];
    const float* Wo = (const float*)d_in[8];

    float* ws = (float*)d_ws;
    const size_t BIG = (size_t)NPIX * HC;
    unsigned* q_pk  = (unsigned*)ws;
    unsigned* k_pk  = (unsigned*)(ws + BIG);
    unsigned* v_pk  = (unsigned*)(ws + 2 * BIG);
    float* g_ws     = ws + 3 * BIG;
    // (slot 4*BIG formerly go_ws -- now unused; offsets kept stable)
    float* bias_n   = ws + 5 * BIG;                            // NH*NPIX floats
    bf16x8* pk      = (bf16x8*)(bias_n + (size_t)NH * NPIX);   // 5 x 64 KB packs

    pack_w_kernel<<<40, 256, 0, stream>>>(Wq, Wk, Wv, Wg, Wo, pk);
    ln_proj_kernel<<<NPIX / 32, 256, 0, stream>>>(z, ls, lb, Wb, pk,
                                                  q_pk, k_pk, v_pk, g_ws, bias_n);
    attn_kernel<<<NN * (NN / 32), 256, 0, stream>>>(q_pk, k_pk, v_pk, g_ws,
                                                    bias_n, pk, (float*)d_out);
}

// Round 11
// 245.685 us; speedup vs baseline: 1.0763x; 1.0763x over previous
//
#include <hip/hip_runtime.h>
#include <math.h>

#define NN 256
#define CZ 128
#define NH 4
#define CH 32
#define HC 128
#define NPIX (NN*NN)
#define L2E   1.4426950408889634f
#define SCALE2 (0.17677669529663687f * 1.4426950408889634f)   // (1/sqrt(32))*log2e

typedef __attribute__((ext_vector_type(8))) short bf16x8;   // 8 bf16 (4 VGPRs)
typedef __attribute__((ext_vector_type(4))) float fx4;      // MFMA accumulator
typedef __attribute__((ext_vector_type(4))) unsigned u32x4;

// --- cheap truncation split: x ~= hi + lo, total err ~2^-16 relative ---
__device__ __forceinline__ unsigned pack_hl(float x) {
    unsigned b  = __builtin_bit_cast(unsigned, x);
    unsigned hb = b & 0xFFFF0000u;
    float r = x - __builtin_bit_cast(float, hb);
    return hb | (__builtin_bit_cast(unsigned, r) >> 16);   // hi in top16, lo in bottom16
}
// load 8 consecutive floats -> hi/lo bf16x8 fragments (trunc split, ~4 VALU/elem)
__device__ __forceinline__ void load_split8(const float* p, bf16x8& h, bf16x8& l) {
    float4 x0 = *(const float4*)p;
    float4 x1 = *(const float4*)(p + 4);
    float xs[8] = {x0.x, x0.y, x0.z, x0.w, x1.x, x1.y, x1.z, x1.w};
    #pragma unroll
    for (int j = 0; j < 8; ++j) {
        unsigned b  = __builtin_bit_cast(unsigned, xs[j]);
        unsigned hb = b & 0xFFFF0000u;
        float r = xs[j] - __builtin_bit_cast(float, hb);
        h[j] = (short)(hb >> 16);
        l[j] = (short)(__builtin_bit_cast(unsigned, r) >> 16);
    }
}
// deinterleave 8 packed uint32 (hi|lo) held in registers -> hi/lo bf16x8 frags
__device__ __forceinline__ void deint_raw(u32x4 e0, u32x4 e1, bf16x8& h, bf16x8& l) {
    unsigned es[8] = {e0[0], e0[1], e0[2], e0[3], e1[0], e1[1], e1[2], e1[3]};
    unsigned hw[4], lw[4];
    #pragma unroll
    for (int j = 0; j < 4; ++j) {
        unsigned a = es[2 * j], b = es[2 * j + 1];
        hw[j] = (a >> 16) | (b & 0xFFFF0000u);
        lw[j] = (a & 0x0000FFFFu) | (b << 16);
    }
    h = __builtin_bit_cast(bf16x8, u32x4{hw[0], hw[1], hw[2], hw[3]});
    l = __builtin_bit_cast(bf16x8, u32x4{lw[0], lw[1], lw[2], lw[3]});
}
// load 8 packed uint32 (hi|lo) -> hi/lo bf16x8 fragments
__device__ __forceinline__ void deint8(const unsigned* p, bf16x8& h, bf16x8& l) {
    u32x4 e0 = *(const u32x4*)p;
    u32x4 e1 = *(const u32x4*)(p + 4);
    deint_raw(e0, e1, h, l);
}

// 2x2x2 quad transpose across lanes (gfx950 dual-dest lane swaps, no LDS).
__device__ __forceinline__ void qtrans(unsigned &x, unsigned &y) {
#if __has_builtin(__builtin_amdgcn_permlane32_swap) && __has_builtin(__builtin_amdgcn_permlane16_swap)
    {
        auto r = __builtin_amdgcn_permlane32_swap(x, y, false, false);
        x = r[0]; y = r[1];
    }
    {
        auto r = __builtin_amdgcn_permlane16_swap(x, y, false, false);
        x = r[0]; y = r[1];
    }
#else
    asm("v_permlane32_swap_b32 %0, %1\n\t"
        "v_permlane16_swap_b32 %0, %1" : "+v"(x), "+v"(y));
#endif
}

// ---------------------------------------------------------------------------
// Kernel 0: pack weights into MFMA B-fragment layout, bf16 hi/lo planes.
// B-frag (16x16x32): lane holds B[k][n], n=lane&15, k=quad*8+j.
// entry index: (kstep*128 + n)*4 + quad. 0=Wq 1=Wk 2=Wv 3=Wg 4=Wo.
// ---------------------------------------------------------------------------
__global__ __launch_bounds__(256) void pack_w_kernel(
    const float* __restrict__ Wq, const float* __restrict__ Wk,
    const float* __restrict__ Wv, const float* __restrict__ Wg,
    const float* __restrict__ Wo, bf16x8* __restrict__ pk)
{
    int id  = blockIdx.x * 256 + threadIdx.x;
    int mid = id >> 11;
    int e   = id & 2047;
    const float* W = (mid == 0) ? Wq : (mid == 1) ? Wk : (mid == 2) ? Wv : (mid == 3) ? Wg : Wo;
    int quad = e & 3, n = (e >> 2) & 127, ks = e >> 9;
    int k0 = ks * 32 + quad * 8;
    bf16x8 h, l;
    #pragma unroll
    for (int j = 0; j < 8; ++j) {
        float x = W[(size_t)(k0 + j) * 128 + n];
        unsigned b  = __builtin_bit_cast(unsigned, x);
        unsigned hb = b & 0xFFFF0000u;
        float r = x - __builtin_bit_cast(float, hb);
        h[j] = (short)(hb >> 16);
        l[j] = (short)(__builtin_bit_cast(unsigned, r) >> 16);
    }
    pk[(size_t)mid * 4096 + e]        = h;
    pk[(size_t)mid * 4096 + 2048 + e] = l;
}

// ---------------------------------------------------------------------------
// Kernel 1: fused LayerNorm + projections via split-bf16 MFMA.
// (round-4 structure; verified passing)
// ---------------------------------------------------------------------------
__global__ __launch_bounds__(256) void ln_proj_kernel(
    const float* __restrict__ z, const float* __restrict__ ls, const float* __restrict__ lb,
    const float* __restrict__ Wb, const bf16x8* __restrict__ pk,
    unsigned* __restrict__ q_pk, unsigned* __restrict__ k_pk, unsigned* __restrict__ v_pk,
    float* __restrict__ g_ws, float* __restrict__ bias_n)
{
    __shared__ float zsh[32][132];
    __shared__ float wbsh[512];

    const int t  = threadIdx.x;
    const int p0 = blockIdx.x * 32;
    const int i  = p0 >> 8;
    const int j0 = p0 & 255;

    wbsh[t]       = Wb[t];
    wbsh[t + 256] = Wb[t + 256];

    const int p = t >> 3, sub = t & 7;
    float4 zv[4];
    {
        const float4* zp = (const float4*)(z + (size_t)(p0 + p) * CZ + sub * 16);
        #pragma unroll
        for (int r = 0; r < 4; ++r) zv[r] = zp[r];
    }
    float s = 0.f, q = 0.f;
    #pragma unroll
    for (int r = 0; r < 4; ++r) {
        s += ((zv[r].x + zv[r].y) + (zv[r].z + zv[r].w));
        q += ((zv[r].x * zv[r].x + zv[r].y * zv[r].y)
            + (zv[r].z * zv[r].z + zv[r].w * zv[r].w));
    }
    #pragma unroll
    for (int m = 1; m <= 4; m <<= 1) {
        s += __shfl_xor(s, m, 64);
        q += __shfl_xor(q, m, 64);
    }
    {
        float mu  = s * (1.0f / 128.0f);
        float var = q * (1.0f / 128.0f) - mu * mu;
        float a   = var + 1e-5f;
        float r0  = rsqrtf(a);
        r0 = r0 * (1.5f - 0.5f * a * r0 * r0);
        #pragma unroll
        for (int r = 0; r < 4; ++r) {
            float4 s4 = ((const float4*)ls)[sub * 4 + r];
            float4 b4 = ((const float4*)lb)[sub * 4 + r];
            float4 v  = zv[r];
            v.x = (v.x - mu) * r0 * s4.x + b4.x;
            v.y = (v.y - mu) * r0 * s4.y + b4.y;
            v.z = (v.z - mu) * r0 * s4.z + b4.z;
            v.w = (v.w - mu) * r0 * s4.w + b4.w;
            *(float4*)&zsh[p][sub * 16 + r * 4] = v;
        }
    }
    __syncthreads();   // the ONLY barrier

    const int wv = t >> 6, lane = t & 63;
    const int lrow = lane & 15, quad = lane >> 4;
    const bf16x8* ph = pk + (size_t)wv * 4096;
    const bf16x8* pl = ph + 2048;

    fx4 acc[2][8];
    #pragma unroll
    for (int mr = 0; mr < 2; ++mr)
        #pragma unroll
        for (int nc = 0; nc < 8; ++nc)
            acc[mr][nc] = fx4{0.f, 0.f, 0.f, 0.f};

    #pragma unroll
    for (int ks = 0; ks < 4; ++ks) {
        bf16x8 ah[2], al[2];
        #pragma unroll
        for (int mr = 0; mr < 2; ++mr)
            load_split8(&zsh[mr * 16 + lrow][ks * 32 + quad * 8], ah[mr], al[mr]);
        #pragma unroll
        for (int nc = 0; nc < 8; ++nc) {
            int bi = (ks * 128 + nc * 16 + lrow) * 4 + quad;
            bf16x8 bh = ph[bi], bl = pl[bi];
            #pragma unroll
            for (int mr = 0; mr < 2; ++mr) {
                acc[mr][nc] = __builtin_amdgcn_mfma_f32_16x16x32_bf16(ah[mr], bl, acc[mr][nc], 0, 0, 0);
                acc[mr][nc] = __builtin_amdgcn_mfma_f32_16x16x32_bf16(al[mr], bh, acc[mr][nc], 0, 0, 0);
                acc[mr][nc] = __builtin_amdgcn_mfma_f32_16x16x32_bf16(ah[mr], bh, acc[mr][nc], 0, 0, 0);
            }
        }
    }

    // epilogue: C layout col=lane&15, row=quad*4+reg
    #pragma unroll
    for (int mr = 0; mr < 2; ++mr) {
        #pragma unroll
        for (int nc = 0; nc < 8; ++nc) {
            int cg = nc * 16 + lrow;          // channel 0..127
            int h = cg >> 5, cc = cg & 31;
            int jl = mr * 16 + quad * 4;      // local pixel base (4 consecutive)
            fx4 a = acc[mr][nc];
            if (wv == 0) {                    // q packed [j][c]
                unsigned* qp = q_pk + ((size_t)(i * NH + h) * NN + j0 + jl) * CH + cc;
                #pragma unroll
                for (int r = 0; r < 4; ++r) qp[r * CH] = pack_hl(a[r]);
            } else if (wv == 1) {             // k packed [j][c]
                unsigned* kp = k_pk + ((size_t)(i * NH + h) * NN + j0 + jl) * CH + cc;
                #pragma unroll
                for (int r = 0; r < 4; ++r) kp[r * CH] = pack_hl(a[r]);
            } else if (wv == 2) {             // v packed transposed [c][j]
                u32x4 e = {pack_hl(a[0]), pack_hl(a[1]), pack_hl(a[2]), pack_hl(a[3])};
                *(u32x4*)(v_pk + ((size_t)(i * NH + h) * CH + cc) * NN + j0 + jl) = e;
            } else {                          // g (fp32)
                float* gp = g_ws + (size_t)(p0 + jl) * HC + cg;
                #pragma unroll
                for (int r = 0; r < 4; ++r) gp[r * HC] = 1.0f / (1.0f + __expf(-a[r]));
            }
        }
    }

    // bias = zn @ Wb * log2e; 2 threads per (hh,p): 64-deep halves + pair add
    {
        int pair = t >> 1, half = t & 1;
        int hh = pair >> 5, pp = pair & 31;
        int d0 = half * 64;
        float b = 0.f;
        #pragma unroll 8
        for (int d = 0; d < 64; ++d)
            b = fmaf(zsh[pp][d0 + d], wbsh[(d0 + d) * 4 + hh], b);
        b += __shfl_xor(b, 1, 64);
        if (half == 0)
            bias_n[(size_t)hh * NPIX + (size_t)i * NN + j0 + pp] = b * L2E;
    }
}

// ---------------------------------------------------------------------------
// Kernel 2: MFMA flash attention + FUSED output projection.
// Block = (i, jb=64-query window); WAVE = HEAD (h=wv). After the gate
// epilogue the block holds all 128 channels x 64 pixels -> LDS (one barrier)
// -> each wave runs the outproj GEMM for 16 pixels and writes `out`.
// XCD-aware dispatch swizzle: the 4 jb-blocks of row i (which share all K/V
// panels) run consecutively on one XCD -> K/V re-reads are L2 hits
// (round-7 verified: FETCH 176->77 MB). Grid=1024=8*128 -> bijective.
// NOTE: round-9/10 plane-format experiment failed correctness (unlocalized);
// reverted to this verified packed+deint path.
// NOTE: plain __launch_bounds__(256) -- (256,4) forced 64-VGPR cap + spill.
// ---------------------------------------------------------------------------
__global__ __launch_bounds__(256) void attn_kernel(
    const unsigned* __restrict__ q_pk, const unsigned* __restrict__ k_pk,
    const unsigned* __restrict__ v_pk, const float* __restrict__ g_ws,
    const float* __restrict__ bias_n, const bf16x8* __restrict__ pk,
    float* __restrict__ out)
{
    __shared__ float gsh[64][132];

    const int t = threadIdx.x;
    const int wv = t >> 6, lane = t & 63;
    const int lrow = lane & 15, quad = lane >> 4;
    // XCD-aware swizzle: 4 jb-blocks of each row i share an XCD, consecutive.
    const int d  = blockIdx.x;
    const int jb = (d >> 3) & 3;
    const int i  = (d & 7) + 8 * (d >> 5);
    const int h = wv;            // wave = head
    const int qb = jb * 64;      // shared 64-query window

    const unsigned* qs = q_pk + (size_t)(i * NH + h) * NN * CH;
    const unsigned* ks = k_pk + (size_t)(i * NH + h) * NN * CH;
    const unsigned* vs = v_pk + (size_t)(i * NH + h) * CH * NN;
    const float*    bs = bias_n + (size_t)h * NPIX;

    bf16x8 qh[4], ql[4];
    #pragma unroll
    for (int nt = 0; nt < 4; ++nt)
        deint8(qs + (size_t)(qb + nt * 16 + lrow) * CH + quad * 8, qh[nt], ql[nt]);

    u32x4 krA[2], krB[2];
    #pragma unroll
    for (int mt = 0; mt < 2; ++mt) {
        const u32x4* kp = (const u32x4*)(ks + (size_t)(mt * 16 + lrow) * CH + quad * 8);
        krA[mt] = kp[0]; krB[mt] = kp[1];
    }

    fx4 oacc[2][4];
    #pragma unroll
    for (int ct = 0; ct < 2; ++ct)
        #pragma unroll
        for (int nt = 0; nt < 4; ++nt)
            oacc[ct][nt] = fx4{0.f, 0.f, 0.f, 0.f};
    float lsum[4] = {0.f, 0.f, 0.f, 0.f};

    for (int kb = 0; kb < NN; kb += 32) {
        u32x4 vrA[2], vrB[2];
        #pragma unroll
        for (int ct = 0; ct < 2; ++ct) {
            const u32x4* vp = (const u32x4*)(vs + (size_t)(ct * 16 + lrow) * NN + kb + quad * 8);
            vrA[ct] = vp[0]; vrB[ct] = vp[1];
        }
        float4 bv[4][2];
        #pragma unroll
        for (int nt = 0; nt < 4; ++nt)
            #pragma unroll
            for (int mt = 0; mt < 2; ++mt)
                bv[nt][mt] = *(const float4*)(bs + (size_t)(qb + nt * 16 + lrow) * NN
                                                 + kb + mt * 16 + quad * 4);
        const int kb2 = (kb + 32) & (NN - 1);
        u32x4 nkA[2], nkB[2];
        #pragma unroll
        for (int mt = 0; mt < 2; ++mt) {
            const u32x4* kp = (const u32x4*)(ks + (size_t)(kb2 + mt * 16 + lrow) * CH + quad * 8);
            nkA[mt] = kp[0]; nkB[mt] = kp[1];
        }

        bf16x8 kh[2], kl_[2];
        #pragma unroll
        for (int mt = 0; mt < 2; ++mt)
            deint_raw(krA[mt], krB[mt], kh[mt], kl_[mt]);

        fx4 sv[4][2];
        __builtin_amdgcn_s_setprio(1);
        #pragma unroll
        for (int nt = 0; nt < 4; ++nt) {
            #pragma unroll
            for (int mt = 0; mt < 2; ++mt) {
                fx4 s = fx4{0.f, 0.f, 0.f, 0.f};
                s = __builtin_amdgcn_mfma_f32_16x16x32_bf16(kh[mt],  ql[nt], s, 0, 0, 0);
                s = __builtin_amdgcn_mfma_f32_16x16x32_bf16(kl_[mt], qh[nt], s, 0, 0, 0);
                s = __builtin_amdgcn_mfma_f32_16x16x32_bf16(kh[mt],  qh[nt], s, 0, 0, 0);
                sv[nt][mt] = s;
            }
        }
        __builtin_amdgcn_s_setprio(0);

        bf16x8 vh[2], vl[2];
        #pragma unroll
        for (int ct = 0; ct < 2; ++ct)
            deint_raw(vrA[ct], vrB[ct], vh[ct], vl[ct]);

        unsigned w0h[4][2], w1h[4][2], w0l[4][2], w1l[4][2];
        #pragma unroll
        for (int nt = 0; nt < 4; ++nt) {
            #pragma unroll
            for (int mt = 0; mt < 2; ++mt) {
                fx4 s = sv[nt][mt];
                float4 b4 = bv[nt][mt];
                float e0 = exp2f(fmaf(s[0], SCALE2, b4.x));
                float e1 = exp2f(fmaf(s[1], SCALE2, b4.y));
                float e2 = exp2f(fmaf(s[2], SCALE2, b4.z));
                float e3 = exp2f(fmaf(s[3], SCALE2, b4.w));
                lsum[nt] += (e0 + e1) + (e2 + e3);

                unsigned b0 = __builtin_bit_cast(unsigned, e0);
                unsigned b1 = __builtin_bit_cast(unsigned, e1);
                unsigned b2 = __builtin_bit_cast(unsigned, e2);
                unsigned b3 = __builtin_bit_cast(unsigned, e3);
                unsigned h01 = (b0 >> 16) | (b1 & 0xFFFF0000u);
                unsigned h23 = (b2 >> 16) | (b3 & 0xFFFF0000u);
                float r0 = e0 - __builtin_bit_cast(float, b0 & 0xFFFF0000u);
                float r1 = e1 - __builtin_bit_cast(float, b1 & 0xFFFF0000u);
                float r2 = e2 - __builtin_bit_cast(float, b2 & 0xFFFF0000u);
                float r3 = e3 - __builtin_bit_cast(float, b3 & 0xFFFF0000u);
                unsigned l01 = (__builtin_bit_cast(unsigned, r0) >> 16)
                             | (__builtin_bit_cast(unsigned, r1) & 0xFFFF0000u);
                unsigned l23 = (__builtin_bit_cast(unsigned, r2) >> 16)
                             | (__builtin_bit_cast(unsigned, r3) & 0xFFFF0000u);
                w0h[nt][mt] = h01; w1h[nt][mt] = h23;
                w0l[nt][mt] = l01; w1l[nt][mt] = l23;
            }
        }

        #pragma unroll
        for (int nt = 0; nt < 4; ++nt) {
            qtrans(w0h[nt][0], w0h[nt][1]);
            qtrans(w1h[nt][0], w1h[nt][1]);
            qtrans(w0l[nt][0], w0l[nt][1]);
            qtrans(w1l[nt][0], w1l[nt][1]);
        }

        __builtin_amdgcn_s_setprio(1);
        #pragma unroll
        for (int nt = 0; nt < 4; ++nt) {
            bf16x8 pbh = __builtin_bit_cast(bf16x8,
                u32x4{w0h[nt][0], w1h[nt][0], w0h[nt][1], w1h[nt][1]});
            bf16x8 pbl = __builtin_bit_cast(bf16x8,
                u32x4{w0l[nt][0], w1l[nt][0], w0l[nt][1], w1l[nt][1]});
            #pragma unroll
            for (int ct = 0; ct < 2; ++ct) {
                oacc[ct][nt] = __builtin_amdgcn_mfma_f32_16x16x32_bf16(vh[ct], pbl, oacc[ct][nt], 0, 0, 0);
                oacc[ct][nt] = __builtin_amdgcn_mfma_f32_16x16x32_bf16(vl[ct], pbh, oacc[ct][nt], 0, 0, 0);
                oacc[ct][nt] = __builtin_amdgcn_mfma_f32_16x16x32_bf16(vh[ct], pbh, oacc[ct][nt], 0, 0, 0);
            }
        }
        __builtin_amdgcn_s_setprio(0);

        #pragma unroll
        for (int mt = 0; mt < 2; ++mt) { krA[mt] = nkA[mt]; krB[mt] = nkB[mt]; }
    }

    // gate epilogue -> LDS [local pixel][channel]; channels h*32..h*32+31
    #pragma unroll
    for (int nt = 0; nt < 4; ++nt) {
        float s = lsum[nt];
        s += __shfl_xor(s, 16, 64);
        s += __shfl_xor(s, 32, 64);
        float inv = 1.0f / s;
        size_t pix = (size_t)i * NN + qb + nt * 16 + lrow;
        #pragma unroll
        for (int ct = 0; ct < 2; ++ct) {
            const float* gp = g_ws + pix * HC + h * CH + ct * 16 + quad * 4;
            float4 g4 = *(const float4*)gp;
            fx4 o = oacc[ct][nt];
            float4 r;
            r.x = g4.x * o[0] * inv;
            r.y = g4.y * o[1] * inv;
            r.z = g4.z * o[2] * inv;
            r.w = g4.w * o[3] * inv;
            *(float4*)&gsh[nt * 16 + lrow][h * CH + ct * 16 + quad * 4] = r;
        }
    }
    __syncthreads();   // only barrier in the kernel

    // fused outproj: wave wv computes local pixels wv*16 .. wv*16+15
    {
        const bf16x8* ph = pk + (size_t)4 * 4096;   // Wo
        const bf16x8* pl = ph + 2048;

        bf16x8 ah[4], al[4];
        #pragma unroll
        for (int ksx = 0; ksx < 4; ++ksx)
            load_split8(&gsh[wv * 16 + lrow][ksx * 32 + quad * 8], ah[ksx], al[ksx]);

        fx4 acc[8];
        #pragma unroll
        for (int nc = 0; nc < 8; ++nc) acc[nc] = fx4{0.f, 0.f, 0.f, 0.f};

        #pragma unroll
        for (int ksx = 0; ksx < 4; ++ksx) {
            #pragma unroll
            for (int nc = 0; nc < 8; ++nc) {
                int bi = (ksx * 128 + nc * 16 + lrow) * 4 + quad;
                bf16x8 bh = ph[bi], bl = pl[bi];
                acc[nc] = __builtin_amdgcn_mfma_f32_16x16x32_bf16(ah[ksx], bl, acc[nc], 0, 0, 0);
                acc[nc] = __builtin_amdgcn_mfma_f32_16x16x32_bf16(al[ksx], bh, acc[nc], 0, 0, 0);
                acc[nc] = __builtin_amdgcn_mfma_f32_16x16x32_bf16(ah[ksx], bh, acc[nc], 0, 0, 0);
            }
        }

        const size_t prow = (size_t)i * NN + qb;
        #pragma unroll
        for (int nc = 0; nc < 8; ++nc) {
            #pragma unroll
            for (int r = 0; r < 4; ++r)
                out[(prow + wv * 16 + quad * 4 + r) * HC + nc * 16 + lrow] = acc[nc][r];
        }
    }
}

// ---------------------------------------------------------------------------
extern "C" void kernel_launch(void* const* d_in, const int* in_sizes, int n_in,
                              void* d_out, int out_size, void* d_ws, size_t ws_size,
                              hipStream_t stream)
{
    const float* z  = (const float*)d_in[0];
    const float* ls = (const float*)d_in[1];
    const float* lb = (const float*)d_in[2];
    const float* Wq = (const float*)d_in[3];
    const float* Wk = (const float*)d_in[4];
    const float* Wv = (const float*)d_in[5];
    const float* Wb = (const float*)d_in[6];
    const float* Wg = (const float*)d_in[7];
    const float* Wo = (const float*)d_in[8];

    float* ws = (float*)d_ws;
    const size_t BIG = (size_t)NPIX * HC;
    unsigned* q_pk  = (unsigned*)ws;
    unsigned* k_pk  = (unsigned*)(ws + BIG);
    unsigned* v_pk  = (unsigned*)(ws + 2 * BIG);
    float* g_ws     = ws + 3 * BIG;
    // (slot 4*BIG unused; offsets kept stable)
    float* bias_n   = ws + 5 * BIG;                            // NH*NPIX floats
    bf16x8* pk      = (bf16x8*)(bias_n + (size_t)NH * NPIX);   // 5 x 64 KB packs

    pack_w_kernel<<<40, 256, 0, stream>>>(Wq, Wk, Wv, Wg, Wo, pk);
    ln_proj_kernel<<<NPIX / 32, 256, 0, stream>>>(z, ls, lb, Wb, pk,
                                                  q_pk, k_pk, v_pk, g_ws, bias_n);
    attn_kernel<<<NN * (NN / 64), 256, 0, stream>>>(q_pk, k_pk, v_pk, g_ws,
                                                    bias_n, pk, (float*)d_out);
}